// Round 1
// baseline (215.445 us; speedup 1.0000x reference)
//
#include <hip/hip_runtime.h>

#define B_  16
#define LC  2048
#define LQ  512
#define DD  128
#define L2E 1.44269504088896340736f

typedef __attribute__((ext_vector_type(8))) short bf16x8;
typedef __attribute__((ext_vector_type(4))) float f32x4;
typedef unsigned short u16;
typedef unsigned int   u32;

#define MFMA(a,b,c) __builtin_amdgcn_mfma_f32_16x16x32_bf16((a),(b),(c),0,0,0)

__device__ __forceinline__ u16 f2bf(float x){
  u32 u = __builtin_bit_cast(u32, x);
  u32 r = (u + 0x7FFFu + ((u >> 16) & 1u)) >> 16;
  return (u16)r;
}
__device__ __forceinline__ float bf2f(u16 h){
  u32 u = ((u32)h) << 16;
  return __builtin_bit_cast(float, u);
}
__device__ __forceinline__ bf16x8 ldb8(const u16* p){
  return *reinterpret_cast<const bf16x8*>(p);
}

// ---------------- K0a: sub0 = C@w4C, sub1 = Q@w4Q ----------------
__global__ void prep_rowdots(const float* __restrict__ C, const float* __restrict__ Q,
                             const float* __restrict__ w4C, const float* __restrict__ w4Q,
                             float* __restrict__ sub0, float* __restrict__ sub1){
  int wid  = (blockIdx.x * blockDim.x + threadIdx.x) >> 6;
  int lane = threadIdx.x & 63;
  if (wid < B_*LC) {
    float2 v = reinterpret_cast<const float2*>(C + (size_t)wid*DD)[lane];
    float2 w = reinterpret_cast<const float2*>(w4C)[lane];
    float s = v.x*w.x + v.y*w.y;
    #pragma unroll
    for (int off = 32; off > 0; off >>= 1) s += __shfl_xor(s, off);
    if (lane == 0) sub0[wid] = s;
  } else {
    int r = wid - B_*LC;
    if (r < B_*LQ) {
      float2 v = reinterpret_cast<const float2*>(Q + (size_t)r*DD)[lane];
      float2 w = reinterpret_cast<const float2*>(w4Q)[lane];
      float s = v.x*w.x + v.y*w.y;
      #pragma unroll
      for (int off = 32; off > 0; off >>= 1) s += __shfl_xor(s, off);
      if (lane == 0) sub1[r] = s;
    }
  }
}

// ---------------- K0b: bf16 staging + transposes ----------------
// blocks 0..255: C tiles -> CwHi/CwLo (row-major) + CbT (transposed)
// blocks 256..319: Q tiles -> Qb (row-major) + QbT (transposed)
__global__ void prep_convert(const float* __restrict__ C, const float* __restrict__ Q,
                             const float* __restrict__ w4mlu,
                             u16* __restrict__ CwHi, u16* __restrict__ CwLo,
                             u16* __restrict__ CbT,  u16* __restrict__ Qb,
                             u16* __restrict__ QbT){
  __shared__ u16 tile[128][130];
  __shared__ float wl[128];
  int t = threadIdx.x;
  int blk = blockIdx.x;
  if (t < 128) wl[t] = w4mlu[t];
  __syncthreads();
  if (blk < 256) {
    int b = blk >> 4, ct = blk & 15, c0 = ct << 7;
    const float* src = C + ((size_t)(b*LC + c0))*DD;
    for (int k = 0; k < 32; ++k) {
      int idx = t + (k << 8);            // over 8192 float2
      int r = idx >> 6, d2 = idx & 63;
      float2 v = reinterpret_cast<const float2*>(src + (size_t)r*DD)[d2];
      float cw0 = v.x * wl[2*d2], cw1 = v.y * wl[2*d2+1];
      u16 h0 = f2bf(cw0), h1 = f2bf(cw1);
      u16 l0 = f2bf(cw0 - bf2f(h0)), l1 = f2bf(cw1 - bf2f(h1));
      size_t o = ((size_t)(b*LC + c0 + r))*DD + 2*d2;
      u32 hh = (u32)h0 | ((u32)h1 << 16);
      u32 ll = (u32)l0 | ((u32)l1 << 16);
      *reinterpret_cast<u32*>(CwHi + o) = hh;
      *reinterpret_cast<u32*>(CwLo + o) = ll;
      tile[r][2*d2]   = f2bf(v.x);
      tile[r][2*d2+1] = f2bf(v.y);
    }
    __syncthreads();
    for (int k = 0; k < 16; ++k) {
      int ch = t + (k << 8);             // 4096 chunks: d row, 4 c's
      int d = ch >> 5, c4 = (ch & 31) << 2;
      u32 lo = (u32)tile[c4][d]   | ((u32)tile[c4+1][d] << 16);
      u32 hi = (u32)tile[c4+2][d] | ((u32)tile[c4+3][d] << 16);
      uint2 u; u.x = lo; u.y = hi;
      *reinterpret_cast<uint2*>(CbT + ((size_t)(b*DD + d))*LC + c0 + c4) = u;
    }
  } else {
    int bq = blk - 256;
    int b = bq >> 2, qt = bq & 3, q0 = qt << 7;
    const float* src = Q + ((size_t)(b*LQ + q0))*DD;
    for (int k = 0; k < 32; ++k) {
      int idx = t + (k << 8);
      int r = idx >> 6, d2 = idx & 63;
      float2 v = reinterpret_cast<const float2*>(src + (size_t)r*DD)[d2];
      u16 h0 = f2bf(v.x), h1 = f2bf(v.y);
      size_t o = ((size_t)(b*LQ + q0 + r))*DD + 2*d2;
      *reinterpret_cast<u32*>(Qb + o) = (u32)h0 | ((u32)h1 << 16);
      tile[r][2*d2]   = h0;
      tile[r][2*d2+1] = h1;
    }
    __syncthreads();
    for (int k = 0; k < 16; ++k) {
      int ch = t + (k << 8);
      int d = ch >> 5, c4 = (ch & 31) << 2;
      u32 lo = (u32)tile[c4][d]   | ((u32)tile[c4+1][d] << 16);
      u32 hi = (u32)tile[c4+2][d] | ((u32)tile[c4+3][d] << 16);
      uint2 u; u.x = lo; u.y = hi;
      *reinterpret_cast<uint2*>(QbT + ((size_t)(b*DD + d))*LQ + q0 + c4) = u;
    }
  }
}

// ---------------- K1: flash column-softmax -> partial T ----------------
// grid 512 = 16 b x 8 qblk(64) x 4 csplit(512). 4 waves, wave = 16 q-rows.
__global__ void flashT(const u16* __restrict__ Qb, const u16* __restrict__ CwHi,
                       const u16* __restrict__ CwLo, const u16* __restrict__ CbT,
                       const float* __restrict__ sub0,
                       float* __restrict__ mPart, float* __restrict__ lPart,
                       float* __restrict__ TaccP){
  __shared__ u16 Pl[64][136];
  int bid = blockIdx.x;
  int id = (bid & 7) * 64 + (bid >> 3);      // XCD swizzle, nwg=512
  int b = id >> 5, qb = (id >> 2) & 7, sp = id & 3;
  int w = threadIdx.x >> 6, l = threadIdx.x & 63;
  int lj = l & 15, lg = l >> 4;
  int q0 = qb*64 + w*16;

  const u16* Qrow = Qb + ((size_t)(b*LQ + q0 + lj))*DD;
  bf16x8 aq[4];
  #pragma unroll
  for (int k = 0; k < 4; ++k) aq[k] = ldb8(Qrow + k*32 + lg*8);

  f32x4 tacc[8];
  #pragma unroll
  for (int f = 0; f < 8; ++f) tacc[f] = (f32x4){0.f,0.f,0.f,0.f};
  float mrow[4], lrow[4];
  #pragma unroll
  for (int r = 0; r < 4; ++r) { mrow[r] = -1e30f; lrow[r] = 0.f; }

  for (int ct = 0; ct < 4; ++ct) {
    int c0 = sp*512 + ct*128;
    f32x4 s[8];
    #pragma unroll
    for (int f = 0; f < 8; ++f) s[f] = (f32x4){0.f,0.f,0.f,0.f};
    #pragma unroll
    for (int ks = 0; ks < 4; ++ks) {
      #pragma unroll
      for (int f = 0; f < 8; ++f) {
        bf16x8 bh = ldb8(CwHi + ((size_t)(b*LC + c0 + f*16 + lj))*DD + ks*32 + lg*8);
        s[f] = MFMA(aq[ks], bh, s[f]);
      }
      #pragma unroll
      for (int f = 0; f < 8; ++f) {
        bf16x8 bl = ldb8(CwLo + ((size_t)(b*LC + c0 + f*16 + lj))*DD + ks*32 + lg*8);
        s[f] = MFMA(aq[ks], bl, s[f]);
      }
    }
    float tm[4] = {-1e30f,-1e30f,-1e30f,-1e30f};
    #pragma unroll
    for (int f = 0; f < 8; ++f) {
      float s0v = sub0[b*LC + c0 + f*16 + lj];
      #pragma unroll
      for (int r = 0; r < 4; ++r) { s[f][r] += s0v; tm[r] = fmaxf(tm[r], s[f][r]); }
    }
    #pragma unroll
    for (int r = 0; r < 4; ++r) {
      #pragma unroll
      for (int m = 1; m < 16; m <<= 1) tm[r] = fmaxf(tm[r], __shfl_xor(tm[r], m));
    }
    float psum[4] = {0.f,0.f,0.f,0.f};
    #pragma unroll
    for (int r = 0; r < 4; ++r) {
      float mn = fmaxf(mrow[r], tm[r]);
      float sc = exp2f((mrow[r] - mn) * L2E);
      lrow[r] *= sc; mrow[r] = mn;
      #pragma unroll
      for (int f = 0; f < 8; ++f) tacc[f][r] *= sc;
    }
    #pragma unroll
    for (int f = 0; f < 8; ++f) {
      #pragma unroll
      for (int r = 0; r < 4; ++r) {
        float p = exp2f((s[f][r] - mrow[r]) * L2E);
        psum[r] += p;
        Pl[w*16 + lg*4 + r][f*16 + lj] = f2bf(p);
      }
    }
    #pragma unroll
    for (int r = 0; r < 4; ++r) {
      #pragma unroll
      for (int m = 1; m < 16; m <<= 1) psum[r] += __shfl_xor(psum[r], m);
      lrow[r] += psum[r];
    }
    // PV: Tacc[q][d] += P[q][c] * C[c][d]  (A from LDS, B from CbT)
    #pragma unroll
    for (int ks2 = 0; ks2 < 4; ++ks2) {
      bf16x8 ap = *reinterpret_cast<const bf16x8*>(&Pl[w*16 + lj][ks2*32 + lg*8]);
      #pragma unroll
      for (int f2 = 0; f2 < 8; ++f2) {
        bf16x8 bv = ldb8(CbT + ((size_t)(b*DD + f2*16 + lj))*LC + c0 + ks2*32 + lg*8);
        tacc[f2] = MFMA(ap, bv, tacc[f2]);
      }
    }
  }
  int pbase = (b*8 + qb)*4 + sp;
  if (lj == 0) {
    #pragma unroll
    for (int r = 0; r < 4; ++r) {
      mPart[pbase*64 + w*16 + lg*4 + r] = mrow[r];
      lPart[pbase*64 + w*16 + lg*4 + r] = lrow[r];
    }
  }
  #pragma unroll
  for (int f = 0; f < 8; ++f) {
    #pragma unroll
    for (int r = 0; r < 4; ++r) {
      TaccP[((size_t)pbase*64 + w*16 + lg*4 + r)*DD + f*16 + lj] = tacc[f][r];
    }
  }
}

// ---------------- K1b: combine c-split partials -> TbT (bf16, transposed) ---
__global__ void combineT(const float* __restrict__ mPart, const float* __restrict__ lPart,
                         const float* __restrict__ TaccP, u16* __restrict__ TbT){
  __shared__ float fac[4][64];
  __shared__ u16 Tt[64][132];
  int blk = blockIdx.x;
  int b = blk >> 3, qb = blk & 7;
  int t = threadIdx.x;
  int base = (b*8 + qb)*4;
  if (t < 64) {
    float m0 = mPart[(base+0)*64 + t], m1 = mPart[(base+1)*64 + t];
    float m2 = mPart[(base+2)*64 + t], m3 = mPart[(base+3)*64 + t];
    float mm = fmaxf(fmaxf(m0,m1), fmaxf(m2,m3));
    float e0 = exp2f((m0-mm)*L2E), e1 = exp2f((m1-mm)*L2E);
    float e2 = exp2f((m2-mm)*L2E), e3 = exp2f((m3-mm)*L2E);
    float lt = lPart[(base+0)*64+t]*e0 + lPart[(base+1)*64+t]*e1
             + lPart[(base+2)*64+t]*e2 + lPart[(base+3)*64+t]*e3;
    float il = 1.0f / lt;
    fac[0][t] = e0*il; fac[1][t] = e1*il; fac[2][t] = e2*il; fac[3][t] = e3*il;
  }
  __syncthreads();
  for (int k = 0; k < 32; ++k) {
    int idx = t + (k << 8); int q = idx >> 7, d = idx & 127;
    float v = TaccP[((size_t)(base+0)*64 + q)*DD + d]*fac[0][q]
            + TaccP[((size_t)(base+1)*64 + q)*DD + d]*fac[1][q]
            + TaccP[((size_t)(base+2)*64 + q)*DD + d]*fac[2][q]
            + TaccP[((size_t)(base+3)*64 + q)*DD + d]*fac[3][q];
    Tt[q][d] = f2bf(v);
  }
  __syncthreads();
  for (int k = 0; k < 8; ++k) {
    int ch = t + (k << 8); int d = ch >> 4, q4 = (ch & 15) << 2;
    u32 lo = (u32)Tt[q4][d]   | ((u32)Tt[q4+1][d] << 16);
    u32 hi = (u32)Tt[q4+2][d] | ((u32)Tt[q4+3][d] << 16);
    uint2 u; u.x = lo; u.y = hi;
    *reinterpret_cast<uint2*>(TbT + ((size_t)(b*DD + d))*LQ + qb*64 + q4) = u;
  }
}

// ---------------- K2: row-softmax + A + Bt + epilogue ----------------
// grid 1024 = 16 b x 64 ctiles(32). 4 waves: phase1 N-split(q), phase2 N-split(d).
__global__ void fused_out(const float* __restrict__ Cf, const u16* __restrict__ CwHi,
                          const u16* __restrict__ CwLo, const u16* __restrict__ Qb,
                          const u16* __restrict__ QbT, const u16* __restrict__ TbT,
                          const float* __restrict__ sub1, float* __restrict__ out){
  __shared__ u16 Pl[32][520];
  __shared__ float red[4][32];
  int bid = blockIdx.x;
  int id = (bid & 7) * 128 + (bid >> 3);     // XCD swizzle, nwg=1024
  int b = id >> 6, ctile = id & 63, c0 = ctile * 32;
  int w = threadIdx.x >> 6, l = threadIdx.x & 63;
  int lj = l & 15, lg = l >> 4;

  f32x4 s[2][8];
  #pragma unroll
  for (int rf = 0; rf < 2; ++rf)
    #pragma unroll
    for (int f = 0; f < 8; ++f) s[rf][f] = (f32x4){0.f,0.f,0.f,0.f};

  #pragma unroll
  for (int ks = 0; ks < 4; ++ks) {
    bf16x8 ah[2], al[2];
    #pragma unroll
    for (int rf = 0; rf < 2; ++rf) {
      size_t ro = ((size_t)(b*LC + c0 + rf*16 + lj))*DD + ks*32 + lg*8;
      ah[rf] = ldb8(CwHi + ro);
      al[rf] = ldb8(CwLo + ro);
    }
    #pragma unroll
    for (int f = 0; f < 8; ++f) {
      bf16x8 qv = ldb8(Qb + ((size_t)(b*LQ + w*128 + f*16 + lj))*DD + ks*32 + lg*8);
      #pragma unroll
      for (int rf = 0; rf < 2; ++rf) {
        s[rf][f] = MFMA(ah[rf], qv, s[rf][f]);
        s[rf][f] = MFMA(al[rf], qv, s[rf][f]);
      }
    }
  }
  float tm[2][4];
  #pragma unroll
  for (int rf = 0; rf < 2; ++rf)
    #pragma unroll
    for (int r = 0; r < 4; ++r) tm[rf][r] = -1e30f;
  #pragma unroll
  for (int f = 0; f < 8; ++f) {
    float s1v = sub1[b*LQ + w*128 + f*16 + lj];
    #pragma unroll
    for (int rf = 0; rf < 2; ++rf)
      #pragma unroll
      for (int r = 0; r < 4; ++r) { s[rf][f][r] += s1v; tm[rf][r] = fmaxf(tm[rf][r], s[rf][f][r]); }
  }
  #pragma unroll
  for (int rf = 0; rf < 2; ++rf)
    #pragma unroll
    for (int r = 0; r < 4; ++r) {
      #pragma unroll
      for (int m = 1; m < 16; m <<= 1) tm[rf][r] = fmaxf(tm[rf][r], __shfl_xor(tm[rf][r], m));
    }
  if (lj == 0) {
    #pragma unroll
    for (int rf = 0; rf < 2; ++rf)
      #pragma unroll
      for (int r = 0; r < 4; ++r) red[w][rf*16 + lg*4 + r] = tm[rf][r];
  }
  __syncthreads();
  float mfin[2][4];
  #pragma unroll
  for (int rf = 0; rf < 2; ++rf)
    #pragma unroll
    for (int r = 0; r < 4; ++r) {
      int row = rf*16 + lg*4 + r;
      mfin[rf][r] = fmaxf(fmaxf(red[0][row], red[1][row]), fmaxf(red[2][row], red[3][row]));
    }
  __syncthreads();
  float ps[2][4] = {{0.f,0.f,0.f,0.f},{0.f,0.f,0.f,0.f}};
  #pragma unroll
  for (int f = 0; f < 8; ++f)
    #pragma unroll
    for (int rf = 0; rf < 2; ++rf)
      #pragma unroll
      for (int r = 0; r < 4; ++r) {
        float p = exp2f((s[rf][f][r] - mfin[rf][r]) * L2E);
        s[rf][f][r] = p;
        ps[rf][r] += p;
      }
  #pragma unroll
  for (int rf = 0; rf < 2; ++rf)
    #pragma unroll
    for (int r = 0; r < 4; ++r) {
      #pragma unroll
      for (int m = 1; m < 16; m <<= 1) ps[rf][r] += __shfl_xor(ps[rf][r], m);
    }
  if (lj == 0) {
    #pragma unroll
    for (int rf = 0; rf < 2; ++rf)
      #pragma unroll
      for (int r = 0; r < 4; ++r) red[w][rf*16 + lg*4 + r] = ps[rf][r];
  }
  __syncthreads();
  float linv[2][4];
  #pragma unroll
  for (int rf = 0; rf < 2; ++rf)
    #pragma unroll
    for (int r = 0; r < 4; ++r) {
      int row = rf*16 + lg*4 + r;
      linv[rf][r] = 1.0f / (red[0][row] + red[1][row] + red[2][row] + red[3][row]);
    }
  #pragma unroll
  for (int f = 0; f < 8; ++f)
    #pragma unroll
    for (int rf = 0; rf < 2; ++rf)
      #pragma unroll
      for (int r = 0; r < 4; ++r)
        Pl[rf*16 + lg*4 + r][w*128 + f*16 + lj] = f2bf(s[rf][f][r]);
  __syncthreads();

  f32x4 aA[2][2], aB[2][2];
  #pragma unroll
  for (int rf = 0; rf < 2; ++rf)
    #pragma unroll
    for (int cf = 0; cf < 2; ++cf) { aA[rf][cf] = (f32x4){0.f,0.f,0.f,0.f}; aB[rf][cf] = (f32x4){0.f,0.f,0.f,0.f}; }
  for (int ks = 0; ks < 16; ++ks) {
    bf16x8 pa[2];
    #pragma unroll
    for (int rf = 0; rf < 2; ++rf)
      pa[rf] = *reinterpret_cast<const bf16x8*>(&Pl[rf*16 + lj][ks*32 + lg*8]);
    #pragma unroll
    for (int cf = 0; cf < 2; ++cf) {
      size_t bo = ((size_t)(b*DD + w*32 + cf*16 + lj))*LQ + ks*32 + lg*8;
      bf16x8 qv = ldb8(QbT + bo);
      bf16x8 tv = ldb8(TbT + bo);
      #pragma unroll
      for (int rf = 0; rf < 2; ++rf) {
        aA[rf][cf] = MFMA(pa[rf], qv, aA[rf][cf]);
        aB[rf][cf] = MFMA(pa[rf], tv, aB[rf][cf]);
      }
    }
  }
  #pragma unroll
  for (int rf = 0; rf < 2; ++rf)
    #pragma unroll
    for (int cf = 0; cf < 2; ++cf)
      #pragma unroll
      for (int r = 0; r < 4; ++r) {
        int cg = c0 + rf*16 + lg*4 + r;
        int d  = w*32 + cf*16 + lj;
        float il = linv[rf][r];
        float Av = aA[rf][cf][r] * il;
        float Bv = aB[rf][cf][r] * il;
        float Cv = Cf[((size_t)(b*LC + cg))*DD + d];
        size_t ob = ((size_t)(b*LC + cg))*512;
        out[ob + d]       = Cv;
        out[ob + 128 + d] = Av;
        out[ob + 256 + d] = Cv*Av;
        out[ob + 384 + d] = Cv*Bv;
      }
}

// ---------------- launch ----------------
extern "C" void kernel_launch(void* const* d_in, const int* in_sizes, int n_in,
                              void* d_out, int out_size, void* d_ws, size_t ws_size,
                              hipStream_t stream) {
  const float* C     = (const float*)d_in[0];
  const float* Q     = (const float*)d_in[1];
  const float* w4C   = (const float*)d_in[4];
  const float* w4Q   = (const float*)d_in[5];
  const float* w4mlu = (const float*)d_in[6];
  float* out = (float*)d_out;

  char* ws = (char*)d_ws;
  size_t off = 0;
  auto alloc = [&](size_t bytes) -> void* {
    void* p = ws + off;
    off += (bytes + 255) & ~(size_t)255;
    return p;
  };
  float* sub0  = (float*)alloc((size_t)B_*LC*4);
  float* sub1  = (float*)alloc((size_t)B_*LQ*4);
  u16*   CwHi  = (u16*)  alloc((size_t)B_*LC*DD*2);
  u16*   CwLo  = (u16*)  alloc((size_t)B_*LC*DD*2);
  u16*   CbT   = (u16*)  alloc((size_t)B_*DD*LC*2);
  u16*   Qb    = (u16*)  alloc((size_t)B_*LQ*DD*2);
  u16*   QbT   = (u16*)  alloc((size_t)B_*DD*LQ*2);
  u16*   TbT   = (u16*)  alloc((size_t)B_*DD*LQ*2);
  float* mPart = (float*)alloc((size_t)B_*8*4*64*4);
  float* lPart = (float*)alloc((size_t)B_*8*4*64*4);
  float* TaccP = (float*)alloc((size_t)B_*8*4*64*DD*4);

  hipLaunchKernelGGL(prep_rowdots, dim3(10240), dim3(256), 0, stream,
                     C, Q, w4C, w4Q, sub0, sub1);
  hipLaunchKernelGGL(prep_convert, dim3(320), dim3(256), 0, stream,
                     C, Q, w4mlu, CwHi, CwLo, CbT, Qb, QbT);
  hipLaunchKernelGGL(flashT, dim3(512), dim3(256), 0, stream,
                     Qb, CwHi, CwLo, CbT, sub0, mPart, lPart, TaccP);
  hipLaunchKernelGGL(combineT, dim3(128), dim3(256), 0, stream,
                     mPart, lPart, TaccP, TbT);
  hipLaunchKernelGGL(fused_out, dim3(1024), dim3(256), 0, stream,
                     C, CwHi, CwLo, Qb, QbT, TbT, sub1, out);
}

// Round 2
// 192.686 us; speedup vs baseline: 1.1181x; 1.1181x over previous
//
#include <hip/hip_runtime.h>

#define B_  16
#define LC  2048
#define LQ  512
#define DD  128
#define L2E 1.44269504088896340736f
#define SP  8

typedef __attribute__((ext_vector_type(8))) short bf16x8;
typedef __attribute__((ext_vector_type(4))) float f32x4;
typedef unsigned short u16;
typedef unsigned int   u32;

#define MFMA(a,b,c) __builtin_amdgcn_mfma_f32_16x16x32_bf16((a),(b),(c),0,0,0)

__device__ __forceinline__ u16 f2bf(float x){
  u32 u = __builtin_bit_cast(u32, x);
  u32 r = (u + 0x7FFFu + ((u >> 16) & 1u)) >> 16;
  return (u16)r;
}
__device__ __forceinline__ float bf2f(u16 h){
  u32 u = ((u32)h) << 16;
  return __builtin_bit_cast(float, u);
}
__device__ __forceinline__ bf16x8 ldb8(const u16* p){
  return *reinterpret_cast<const bf16x8*>(p);
}

// ---------------- K0a: sub0 = C@w4C, sub1 = Q@w4Q ----------------
__global__ void prep_rowdots(const float* __restrict__ C, const float* __restrict__ Q,
                             const float* __restrict__ w4C, const float* __restrict__ w4Q,
                             float* __restrict__ sub0, float* __restrict__ sub1){
  int wid  = (blockIdx.x * blockDim.x + threadIdx.x) >> 6;
  int lane = threadIdx.x & 63;
  if (wid < B_*LC) {
    float2 v = reinterpret_cast<const float2*>(C + (size_t)wid*DD)[lane];
    float2 w = reinterpret_cast<const float2*>(w4C)[lane];
    float s = v.x*w.x + v.y*w.y;
    #pragma unroll
    for (int off = 32; off > 0; off >>= 1) s += __shfl_xor(s, off);
    if (lane == 0) sub0[wid] = s;
  } else {
    int r = wid - B_*LC;
    if (r < B_*LQ) {
      float2 v = reinterpret_cast<const float2*>(Q + (size_t)r*DD)[lane];
      float2 w = reinterpret_cast<const float2*>(w4Q)[lane];
      float s = v.x*w.x + v.y*w.y;
      #pragma unroll
      for (int off = 32; off > 0; off >>= 1) s += __shfl_xor(s, off);
      if (lane == 0) sub1[r] = s;
    }
  }
}

// ---------------- K0b: bf16 staging + transposes ----------------
__global__ void prep_convert(const float* __restrict__ C, const float* __restrict__ Q,
                             const float* __restrict__ w4mlu,
                             u16* __restrict__ Cwb, u16* __restrict__ CbT,
                             u16* __restrict__ Qb,  u16* __restrict__ QbT){
  __shared__ u16 tile[128][130];
  __shared__ float wl[128];
  int t = threadIdx.x;
  int blk = blockIdx.x;
  if (t < 128) wl[t] = w4mlu[t];
  __syncthreads();
  if (blk < 256) {
    int b = blk >> 4, ct = blk & 15, c0 = ct << 7;
    const float* src = C + ((size_t)(b*LC + c0))*DD;
    for (int k = 0; k < 32; ++k) {
      int idx = t + (k << 8);
      int r = idx >> 6, d2 = idx & 63;
      float2 v = reinterpret_cast<const float2*>(src + (size_t)r*DD)[d2];
      float cw0 = v.x * wl[2*d2], cw1 = v.y * wl[2*d2+1];
      u16 h0 = f2bf(cw0), h1 = f2bf(cw1);
      size_t o = ((size_t)(b*LC + c0 + r))*DD + 2*d2;
      *reinterpret_cast<u32*>(Cwb + o) = (u32)h0 | ((u32)h1 << 16);
      tile[r][2*d2]   = f2bf(v.x);
      tile[r][2*d2+1] = f2bf(v.y);
    }
    __syncthreads();
    for (int k = 0; k < 16; ++k) {
      int ch = t + (k << 8);
      int d = ch >> 5, c4 = (ch & 31) << 2;
      u32 lo = (u32)tile[c4][d]   | ((u32)tile[c4+1][d] << 16);
      u32 hi = (u32)tile[c4+2][d] | ((u32)tile[c4+3][d] << 16);
      uint2 u; u.x = lo; u.y = hi;
      *reinterpret_cast<uint2*>(CbT + ((size_t)(b*DD + d))*LC + c0 + c4) = u;
    }
  } else {
    int bq = blk - 256;
    int b = bq >> 2, qt = bq & 3, q0 = qt << 7;
    const float* src = Q + ((size_t)(b*LQ + q0))*DD;
    for (int k = 0; k < 32; ++k) {
      int idx = t + (k << 8);
      int r = idx >> 6, d2 = idx & 63;
      float2 v = reinterpret_cast<const float2*>(src + (size_t)r*DD)[d2];
      u16 h0 = f2bf(v.x), h1 = f2bf(v.y);
      size_t o = ((size_t)(b*LQ + q0 + r))*DD + 2*d2;
      *reinterpret_cast<u32*>(Qb + o) = (u32)h0 | ((u32)h1 << 16);
      tile[r][2*d2]   = h0;
      tile[r][2*d2+1] = h1;
    }
    __syncthreads();
    for (int k = 0; k < 16; ++k) {
      int ch = t + (k << 8);
      int d = ch >> 5, c4 = (ch & 31) << 2;
      u32 lo = (u32)tile[c4][d]   | ((u32)tile[c4+1][d] << 16);
      u32 hi = (u32)tile[c4+2][d] | ((u32)tile[c4+3][d] << 16);
      uint2 u; u.x = lo; u.y = hi;
      *reinterpret_cast<uint2*>(QbT + ((size_t)(b*DD + d))*LQ + q0 + c4) = u;
    }
  }
}

// ---------------- K1: flash column-softmax -> partial T ----------------
// grid 1024 = 16 b x 8 qblk(64) x 8 csplit(256). 4 waves, wave = 16 q-rows.
__global__ void flashT(const u16* __restrict__ Qb, const u16* __restrict__ Cwb,
                       const u16* __restrict__ CbT, const float* __restrict__ sub0,
                       float* __restrict__ mPart, float* __restrict__ lPart,
                       u16* __restrict__ TaccP){
  __shared__ u16 Pl[64][136];
  int bid = blockIdx.x;
  int id = (bid & 7) * 128 + (bid >> 3);      // XCD swizzle, nwg=1024
  int b = id >> 6, qb = (id >> 3) & 7, sp = id & 7;
  int w = threadIdx.x >> 6, l = threadIdx.x & 63;
  int lj = l & 15, lg = l >> 4;
  int q0 = qb*64 + w*16;

  const u16* Qrow = Qb + ((size_t)(b*LQ + q0 + lj))*DD;
  bf16x8 aq[4];
  #pragma unroll
  for (int k = 0; k < 4; ++k) aq[k] = ldb8(Qrow + k*32 + lg*8);

  f32x4 tacc[8];
  #pragma unroll
  for (int f = 0; f < 8; ++f) tacc[f] = (f32x4){0.f,0.f,0.f,0.f};
  float mrow[4], lrow[4];
  #pragma unroll
  for (int r = 0; r < 4; ++r) { mrow[r] = -1e30f; lrow[r] = 0.f; }

  for (int ct = 0; ct < 2; ++ct) {
    int c0 = sp*256 + ct*128;
    f32x4 s[8];
    #pragma unroll
    for (int f = 0; f < 8; ++f) s[f] = (f32x4){0.f,0.f,0.f,0.f};
    #pragma unroll
    for (int ks = 0; ks < 4; ++ks) {
      #pragma unroll
      for (int f = 0; f < 8; ++f) {
        bf16x8 bh = ldb8(Cwb + ((size_t)(b*LC + c0 + f*16 + lj))*DD + ks*32 + lg*8);
        s[f] = MFMA(aq[ks], bh, s[f]);
      }
    }
    float tm[4] = {-1e30f,-1e30f,-1e30f,-1e30f};
    #pragma unroll
    for (int f = 0; f < 8; ++f) {
      float s0v = sub0[b*LC + c0 + f*16 + lj];
      #pragma unroll
      for (int r = 0; r < 4; ++r) { s[f][r] += s0v; tm[r] = fmaxf(tm[r], s[f][r]); }
    }
    #pragma unroll
    for (int r = 0; r < 4; ++r) {
      #pragma unroll
      for (int m = 1; m < 16; m <<= 1) tm[r] = fmaxf(tm[r], __shfl_xor(tm[r], m));
    }
    float psum[4] = {0.f,0.f,0.f,0.f};
    #pragma unroll
    for (int r = 0; r < 4; ++r) {
      float mn = fmaxf(mrow[r], tm[r]);
      float sc = exp2f((mrow[r] - mn) * L2E);
      lrow[r] *= sc; mrow[r] = mn;
      #pragma unroll
      for (int f = 0; f < 8; ++f) tacc[f][r] *= sc;
    }
    #pragma unroll
    for (int f = 0; f < 8; ++f) {
      #pragma unroll
      for (int r = 0; r < 4; ++r) {
        float p = exp2f((s[f][r] - mrow[r]) * L2E);
        psum[r] += p;
        Pl[w*16 + lg*4 + r][f*16 + lj] = f2bf(p);
      }
    }
    #pragma unroll
    for (int r = 0; r < 4; ++r) {
      #pragma unroll
      for (int m = 1; m < 16; m <<= 1) psum[r] += __shfl_xor(psum[r], m);
      lrow[r] += psum[r];
    }
    #pragma unroll
    for (int ks2 = 0; ks2 < 4; ++ks2) {
      bf16x8 ap = *reinterpret_cast<const bf16x8*>(&Pl[w*16 + lj][ks2*32 + lg*8]);
      #pragma unroll
      for (int f2 = 0; f2 < 8; ++f2) {
        bf16x8 bv = ldb8(CbT + ((size_t)(b*DD + f2*16 + lj))*LC + c0 + ks2*32 + lg*8);
        tacc[f2] = MFMA(ap, bv, tacc[f2]);
      }
    }
  }
  int pbase = (b*8 + qb)*SP + sp;
  if (lj == 0) {
    #pragma unroll
    for (int r = 0; r < 4; ++r) {
      mPart[pbase*64 + w*16 + lg*4 + r] = mrow[r];
      lPart[pbase*64 + w*16 + lg*4 + r] = lrow[r];
    }
  }
  #pragma unroll
  for (int f = 0; f < 8; ++f) {
    ushort4 hv;
    hv.x = f2bf(tacc[f][0]); hv.y = f2bf(tacc[f][1]);
    hv.z = f2bf(tacc[f][2]); hv.w = f2bf(tacc[f][3]);
    *reinterpret_cast<ushort4*>(TaccP + (((size_t)pbase*4 + w)*8 + f)*256 + lj*16 + lg*4) = hv;
  }
}

// ---------------- K1b: combine c-split partials -> TbT ----------------
__global__ void combineT(const float* __restrict__ mPart, const float* __restrict__ lPart,
                         const u16* __restrict__ TaccP, u16* __restrict__ TbT){
  __shared__ float fac[SP][64];
  __shared__ u16 Tt[64][132];
  int blk = blockIdx.x;
  int b = blk >> 3, qb = blk & 7;
  int t = threadIdx.x;
  int base = (b*8 + qb)*SP;
  if (t < 64) {
    float m_[SP], mm = -1e30f;
    #pragma unroll
    for (int p = 0; p < SP; ++p) { m_[p] = mPart[(base+p)*64 + t]; mm = fmaxf(mm, m_[p]); }
    float lt = 0.f, e[SP];
    #pragma unroll
    for (int p = 0; p < SP; ++p) {
      e[p] = exp2f((m_[p] - mm) * L2E);
      lt += lPart[(base+p)*64 + t] * e[p];
    }
    float il = 1.0f / lt;
    #pragma unroll
    for (int p = 0; p < SP; ++p) fac[p][t] = e[p] * il;
  }
  __syncthreads();
  int lj = t >> 4, lg = (t >> 2) & 3, r = t & 3;
  for (int w = 0; w < 4; ++w) {
    int q = w*16 + lg*4 + r;
    for (int f = 0; f < 8; ++f) {
      float acc = 0.f;
      #pragma unroll
      for (int p = 0; p < SP; ++p)
        acc += bf2f(TaccP[(((size_t)(base+p)*4 + w)*8 + f)*256 + t]) * fac[p][q];
      Tt[q][f*16 + lj] = f2bf(acc);
    }
  }
  __syncthreads();
  for (int k = 0; k < 8; ++k) {
    int ch = t + (k << 8); int d = ch >> 4, q4 = (ch & 15) << 2;
    u32 lo = (u32)Tt[q4][d]   | ((u32)Tt[q4+1][d] << 16);
    u32 hi = (u32)Tt[q4+2][d] | ((u32)Tt[q4+3][d] << 16);
    uint2 u; u.x = lo; u.y = hi;
    *reinterpret_cast<uint2*>(TbT + ((size_t)(b*DD + d))*LQ + qb*64 + q4) = u;
  }
}

// ---------------- K2: row-softmax + A + Bt + epilogue ----------------
__global__ void fused_out(const float* __restrict__ Cf, const u16* __restrict__ Cwb,
                          const u16* __restrict__ Qb, const u16* __restrict__ QbT,
                          const u16* __restrict__ TbT, const float* __restrict__ sub1,
                          float* __restrict__ out){
  __shared__ char smem[33792];
  __shared__ float red[4][32];
  u16*   Pl  = (u16*)smem;              // [32][520]
  float* avl = (float*)smem;            // [32][132]
  float* bvl = avl + 32*132;
  int bid = blockIdx.x;
  int id = (bid & 7) * 128 + (bid >> 3);
  int b = id >> 6, ctile = id & 63, c0 = ctile * 32;
  int w = threadIdx.x >> 6, l = threadIdx.x & 63;
  int lj = l & 15, lg = l >> 4;

  f32x4 s[2][8];
  #pragma unroll
  for (int rf = 0; rf < 2; ++rf)
    #pragma unroll
    for (int f = 0; f < 8; ++f) s[rf][f] = (f32x4){0.f,0.f,0.f,0.f};

  #pragma unroll
  for (int ks = 0; ks < 4; ++ks) {
    bf16x8 ah[2];
    #pragma unroll
    for (int rf = 0; rf < 2; ++rf)
      ah[rf] = ldb8(Cwb + ((size_t)(b*LC + c0 + rf*16 + lj))*DD + ks*32 + lg*8);
    #pragma unroll
    for (int f = 0; f < 8; ++f) {
      bf16x8 qv = ldb8(Qb + ((size_t)(b*LQ + w*128 + f*16 + lj))*DD + ks*32 + lg*8);
      #pragma unroll
      for (int rf = 0; rf < 2; ++rf) s[rf][f] = MFMA(ah[rf], qv, s[rf][f]);
    }
  }
  float tm[2][4];
  #pragma unroll
  for (int rf = 0; rf < 2; ++rf)
    #pragma unroll
    for (int r = 0; r < 4; ++r) tm[rf][r] = -1e30f;
  #pragma unroll
  for (int f = 0; f < 8; ++f) {
    float s1v = sub1[b*LQ + w*128 + f*16 + lj];
    #pragma unroll
    for (int rf = 0; rf < 2; ++rf)
      #pragma unroll
      for (int r = 0; r < 4; ++r) { s[rf][f][r] += s1v; tm[rf][r] = fmaxf(tm[rf][r], s[rf][f][r]); }
  }
  #pragma unroll
  for (int rf = 0; rf < 2; ++rf)
    #pragma unroll
    for (int r = 0; r < 4; ++r) {
      #pragma unroll
      for (int m = 1; m < 16; m <<= 1) tm[rf][r] = fmaxf(tm[rf][r], __shfl_xor(tm[rf][r], m));
    }
  if (lj == 0) {
    #pragma unroll
    for (int rf = 0; rf < 2; ++rf)
      #pragma unroll
      for (int r = 0; r < 4; ++r) red[w][rf*16 + lg*4 + r] = tm[rf][r];
  }
  __syncthreads();
  float mfin[2][4];
  #pragma unroll
  for (int rf = 0; rf < 2; ++rf)
    #pragma unroll
    for (int r = 0; r < 4; ++r) {
      int row = rf*16 + lg*4 + r;
      mfin[rf][r] = fmaxf(fmaxf(red[0][row], red[1][row]), fmaxf(red[2][row], red[3][row]));
    }
  __syncthreads();
  float ps[2][4] = {{0.f,0.f,0.f,0.f},{0.f,0.f,0.f,0.f}};
  #pragma unroll
  for (int f = 0; f < 8; ++f)
    #pragma unroll
    for (int rf = 0; rf < 2; ++rf)
      #pragma unroll
      for (int r = 0; r < 4; ++r) {
        float p = exp2f((s[rf][f][r] - mfin[rf][r]) * L2E);
        s[rf][f][r] = p;
        ps[rf][r] += p;
      }
  #pragma unroll
  for (int rf = 0; rf < 2; ++rf)
    #pragma unroll
    for (int r = 0; r < 4; ++r) {
      #pragma unroll
      for (int m = 1; m < 16; m <<= 1) ps[rf][r] += __shfl_xor(ps[rf][r], m);
    }
  if (lj == 0) {
    #pragma unroll
    for (int rf = 0; rf < 2; ++rf)
      #pragma unroll
      for (int r = 0; r < 4; ++r) red[w][rf*16 + lg*4 + r] = ps[rf][r];
  }
  __syncthreads();
  float linv[2][4];
  #pragma unroll
  for (int rf = 0; rf < 2; ++rf)
    #pragma unroll
    for (int r = 0; r < 4; ++r) {
      int row = rf*16 + lg*4 + r;
      linv[rf][r] = 1.0f / (red[0][row] + red[1][row] + red[2][row] + red[3][row]);
    }
  #pragma unroll
  for (int f = 0; f < 8; ++f)
    #pragma unroll
    for (int rf = 0; rf < 2; ++rf)
      #pragma unroll
      for (int r = 0; r < 4; ++r)
        Pl[(rf*16 + lg*4 + r)*520 + w*128 + f*16 + lj] = f2bf(s[rf][f][r]);
  __syncthreads();

  f32x4 aA[2][2], aB[2][2];
  #pragma unroll
  for (int rf = 0; rf < 2; ++rf)
    #pragma unroll
    for (int cf = 0; cf < 2; ++cf) { aA[rf][cf] = (f32x4){0.f,0.f,0.f,0.f}; aB[rf][cf] = (f32x4){0.f,0.f,0.f,0.f}; }
  for (int ks = 0; ks < 16; ++ks) {
    bf16x8 pa[2];
    #pragma unroll
    for (int rf = 0; rf < 2; ++rf)
      pa[rf] = ldb8(Pl + (rf*16 + lj)*520 + ks*32 + lg*8);
    #pragma unroll
    for (int cf = 0; cf < 2; ++cf) {
      size_t bo = ((size_t)(b*DD + w*32 + cf*16 + lj))*LQ + ks*32 + lg*8;
      bf16x8 qv = ldb8(QbT + bo);
      bf16x8 tv = ldb8(TbT + bo);
      #pragma unroll
      for (int rf = 0; rf < 2; ++rf) {
        aA[rf][cf] = MFMA(pa[rf], qv, aA[rf][cf]);
        aB[rf][cf] = MFMA(pa[rf], tv, aB[rf][cf]);
      }
    }
  }
  __syncthreads();
  #pragma unroll
  for (int rf = 0; rf < 2; ++rf)
    #pragma unroll
    for (int cf = 0; cf < 2; ++cf)
      #pragma unroll
      for (int r = 0; r < 4; ++r) {
        int row = rf*16 + lg*4 + r;
        int d   = w*32 + cf*16 + lj;
        avl[row*132 + d] = aA[rf][cf][r] * linv[rf][r];
        bvl[row*132 + d] = aB[rf][cf][r] * linv[rf][r];
      }
  __syncthreads();
  for (int i = 0; i < 16; ++i) {
    int row = i*2 + (l >> 5), d4 = l & 31;
    size_t grow = (size_t)(b*LC + c0 + row);
    float4 o;
    if (w == 0) {
      o = *reinterpret_cast<const float4*>(Cf + grow*DD + d4*4);
    } else if (w == 1) {
      o = *reinterpret_cast<const float4*>(avl + row*132 + d4*4);
    } else if (w == 2) {
      float4 c = *reinterpret_cast<const float4*>(Cf + grow*DD + d4*4);
      float4 a = *reinterpret_cast<const float4*>(avl + row*132 + d4*4);
      o.x = c.x*a.x; o.y = c.y*a.y; o.z = c.z*a.z; o.w = c.w*a.w;
    } else {
      float4 c = *reinterpret_cast<const float4*>(Cf + grow*DD + d4*4);
      float4 bb = *reinterpret_cast<const float4*>(bvl + row*132 + d4*4);
      o.x = c.x*bb.x; o.y = c.y*bb.y; o.z = c.z*bb.z; o.w = c.w*bb.w;
    }
    *reinterpret_cast<float4*>(out + grow*512 + w*128 + d4*4) = o;
  }
}

// ---------------- launch ----------------
extern "C" void kernel_launch(void* const* d_in, const int* in_sizes, int n_in,
                              void* d_out, int out_size, void* d_ws, size_t ws_size,
                              hipStream_t stream) {
  const float* C     = (const float*)d_in[0];
  const float* Q     = (const float*)d_in[1];
  const float* w4C   = (const float*)d_in[4];
  const float* w4Q   = (const float*)d_in[5];
  const float* w4mlu = (const float*)d_in[6];
  float* out = (float*)d_out;

  char* ws = (char*)d_ws;
  size_t off = 0;
  auto alloc = [&](size_t bytes) -> void* {
    void* p = ws + off;
    off += (bytes + 255) & ~(size_t)255;
    return p;
  };
  float* sub0  = (float*)alloc((size_t)B_*LC*4);
  float* sub1  = (float*)alloc((size_t)B_*LQ*4);
  u16*   Cwb   = (u16*)  alloc((size_t)B_*LC*DD*2);
  u16*   CbT   = (u16*)  alloc((size_t)B_*DD*LC*2);
  u16*   Qb    = (u16*)  alloc((size_t)B_*LQ*DD*2);
  u16*   QbT   = (u16*)  alloc((size_t)B_*DD*LQ*2);
  u16*   TbT   = (u16*)  alloc((size_t)B_*DD*LQ*2);
  float* mPart = (float*)alloc((size_t)B_*8*SP*64*4);
  float* lPart = (float*)alloc((size_t)B_*8*SP*64*4);
  u16*   TaccP = (u16*)  alloc((size_t)B_*8*SP*64*DD*2);

  hipLaunchKernelGGL(prep_rowdots, dim3(10240), dim3(256), 0, stream,
                     C, Q, w4C, w4Q, sub0, sub1);
  hipLaunchKernelGGL(prep_convert, dim3(320), dim3(256), 0, stream,
                     C, Q, w4mlu, Cwb, CbT, Qb, QbT);
  hipLaunchKernelGGL(flashT, dim3(1024), dim3(256), 0, stream,
                     Qb, Cwb, CbT, sub0, mPart, lPart, TaccP);
  hipLaunchKernelGGL(combineT, dim3(128), dim3(256), 0, stream,
                     mPart, lPart, TaccP, TbT);
  hipLaunchKernelGGL(fused_out, dim3(1024), dim3(256), 0, stream,
                     C, Cwb, Qb, QbT, TbT, sub1, out);
}

// Round 3
// 112.705 us; speedup vs baseline: 1.9116x; 1.7097x over previous
//
#include <hip/hip_runtime.h>

#define B_  16
#define LC  2048
#define LQ  512
#define DD  128
#define L2E 1.44269504088896340736f
#define SP  16

typedef __attribute__((ext_vector_type(8))) short bf16x8;
typedef __attribute__((ext_vector_type(4))) float f32x4;
typedef unsigned short u16;
typedef unsigned int   u32;

#define MFMA(a,b,c) __builtin_amdgcn_mfma_f32_16x16x32_bf16((a),(b),(c),0,0,0)

__device__ __forceinline__ u16 f2bf(float x){
  u32 u = __builtin_bit_cast(u32, x);
  u32 r = (u + 0x7FFFu + ((u >> 16) & 1u)) >> 16;
  return (u16)r;
}
__device__ __forceinline__ float bf2f(u16 h){
  u32 u = ((u32)h) << 16;
  return __builtin_bit_cast(float, u);
}
__device__ __forceinline__ bf16x8 ldb8(const u16* p){
  return *reinterpret_cast<const bf16x8*>(p);
}
// swizzled LDS read addr for a [128 rows][256B] tile: byte ^= (row&7)<<4
__device__ __forceinline__ const u16* swz(const u16* base, int row, int colb){
  return base + (row << 7) + ((colb ^ ((row & 7) << 4)) >> 1);
}
#define GLOAD_LDS(g, l) \
  __builtin_amdgcn_global_load_lds((const __attribute__((address_space(1))) void*)(g), \
                                   (__attribute__((address_space(3))) void*)(l), 16, 0, 0)

// ---------------- K0: bf16 staging + transposes + row-dots ----------------
// blocks 0..511: C 64-row tiles -> Cwb, CbT, sub0
// blocks 512..639: Q 64-row tiles -> Qb, QbT, sub1
__global__ void prep(const float* __restrict__ C, const float* __restrict__ Q,
                     const float* __restrict__ w4C, const float* __restrict__ w4Q,
                     const float* __restrict__ w4mlu,
                     u16* __restrict__ Cwb, u16* __restrict__ CbT,
                     u16* __restrict__ Qb,  u16* __restrict__ QbT,
                     float* __restrict__ sub0, float* __restrict__ sub1){
  __shared__ u16 tile[64][130];
  __shared__ float wl[128];
  int t = threadIdx.x, blk = blockIdx.x;
  int lane = t & 63;
  bool isC = blk < 512;
  if (t < 128) wl[t] = w4mlu[t];
  __syncthreads();
  float2 wv = reinterpret_cast<const float2*>(isC ? w4C : w4Q)[lane];
  if (isC) {
    int b = blk >> 5, ct = blk & 31, c0 = ct << 6;
    const float* src = C + ((size_t)(b*LC + c0))*DD;
    for (int k = 0; k < 16; ++k) {
      int idx = t + (k << 8);
      int r = idx >> 6, d2 = idx & 63;
      float2 v = reinterpret_cast<const float2*>(src + (size_t)r*DD)[d2];
      float sdot = v.x*wv.x + v.y*wv.y;
      #pragma unroll
      for (int o = 32; o > 0; o >>= 1) sdot += __shfl_xor(sdot, o);
      if (lane == 0) sub0[b*LC + c0 + r] = sdot;
      float cw0 = v.x * wl[2*d2], cw1 = v.y * wl[2*d2+1];
      size_t o = ((size_t)(b*LC + c0 + r))*DD + 2*d2;
      *reinterpret_cast<u32*>(Cwb + o) = (u32)f2bf(cw0) | ((u32)f2bf(cw1) << 16);
      tile[r][2*d2]   = f2bf(v.x);
      tile[r][2*d2+1] = f2bf(v.y);
    }
    __syncthreads();
    for (int k = 0; k < 8; ++k) {
      int ch = t + (k << 8);            // 2048 chunks: 128 d x 16 groups of 4 c
      int d = ch >> 4, c4 = (ch & 15) << 2;
      u32 lo = (u32)tile[c4][d]   | ((u32)tile[c4+1][d] << 16);
      u32 hi = (u32)tile[c4+2][d] | ((u32)tile[c4+3][d] << 16);
      uint2 u; u.x = lo; u.y = hi;
      *reinterpret_cast<uint2*>(CbT + ((size_t)(b*DD + d))*LC + c0 + c4) = u;
    }
  } else {
    int bq = blk - 512;
    int b = bq >> 3, qt = bq & 7, q0 = qt << 6;
    const float* src = Q + ((size_t)(b*LQ + q0))*DD;
    for (int k = 0; k < 16; ++k) {
      int idx = t + (k << 8);
      int r = idx >> 6, d2 = idx & 63;
      float2 v = reinterpret_cast<const float2*>(src + (size_t)r*DD)[d2];
      float sdot = v.x*wv.x + v.y*wv.y;
      #pragma unroll
      for (int o = 32; o > 0; o >>= 1) sdot += __shfl_xor(sdot, o);
      if (lane == 0) sub1[b*LQ + q0 + r] = sdot;
      u16 h0 = f2bf(v.x), h1 = f2bf(v.y);
      size_t o = ((size_t)(b*LQ + q0 + r))*DD + 2*d2;
      *reinterpret_cast<u32*>(Qb + o) = (u32)h0 | ((u32)h1 << 16);
      tile[r][2*d2]   = h0;
      tile[r][2*d2+1] = h1;
    }
    __syncthreads();
    for (int k = 0; k < 8; ++k) {
      int ch = t + (k << 8);
      int d = ch >> 4, c4 = (ch & 15) << 2;
      u32 lo = (u32)tile[c4][d]   | ((u32)tile[c4+1][d] << 16);
      u32 hi = (u32)tile[c4+2][d] | ((u32)tile[c4+3][d] << 16);
      uint2 u; u.x = lo; u.y = hi;
      *reinterpret_cast<uint2*>(QbT + ((size_t)(b*DD + d))*LQ + q0 + c4) = u;
    }
  }
}

// ---------------- K1: flash column-softmax -> partial T ----------------
// grid 2048 = 16 b x 8 qblk(64) x 16 csplit(128). 4 waves, wave = 16 q-rows.
// One 128-c tile per block; Cwb then CbT staged through one swizzled LDS buffer.
__global__ __launch_bounds__(256, 3)
void flashT(const u16* __restrict__ Qb, const u16* __restrict__ Cwb,
            const u16* __restrict__ CbT, const float* __restrict__ sub0,
            float* __restrict__ mPart, float* __restrict__ lPart,
            u16* __restrict__ TaccP){
  __shared__ __align__(16) u16 buf[128*128];   // 32KB swizzled tile
  __shared__ u16 Pl[64][136];
  int bid = blockIdx.x;
  int id = (bid & 7) * 256 + (bid >> 3);       // XCD swizzle, nwg=2048
  int b = id >> 7, qb = (id >> 4) & 7, sp = id & 15;
  int c0 = sp * 128;
  int w = threadIdx.x >> 6, l = threadIdx.x & 63;
  int lj = l & 15, lg = l >> 4;

  // stage Cwb tile (rows c, 256B each, contiguous 32KB) with pre-swizzled source
  {
    const char* gb = (const char*)(Cwb + ((size_t)(b*LC + c0))*DD);
    #pragma unroll
    for (int i = 0; i < 8; ++i) {
      int off = (w*8 + i)*1024 + l*16;
      int row = off >> 8, col = off & 255;
      int src = (row << 8) | (col ^ ((row & 7) << 4));
      GLOAD_LDS(gb + src, (char*)buf + off);
    }
  }
  // per-wave Q fragments + sub0 values (block-fixed)
  const u16* Qrow = Qb + ((size_t)(b*LQ + qb*64 + w*16 + lj))*DD;
  bf16x8 aq[4];
  #pragma unroll
  for (int k = 0; k < 4; ++k) aq[k] = ldb8(Qrow + k*32 + lg*8);
  float s0v[8];
  #pragma unroll
  for (int f = 0; f < 8; ++f) s0v[f] = sub0[b*LC + c0 + f*16 + lj];
  __syncthreads();

  // QK^T from LDS
  f32x4 s[8];
  #pragma unroll
  for (int f = 0; f < 8; ++f) s[f] = (f32x4){0.f,0.f,0.f,0.f};
  #pragma unroll
  for (int ks = 0; ks < 4; ++ks) {
    #pragma unroll
    for (int f = 0; f < 8; ++f)
      s[f] = MFMA(aq[ks], ldb8(swz(buf, f*16 + lj, ks*64 + lg*16)), s[f]);
  }
  __syncthreads();     // all waves done reading buf

  // stage CbT tile (rows d, 256B each, row stride LC*2) — latency hidden by softmax
  {
    const char* gb = (const char*)CbT + ((size_t)b*DD)*LC*2 + (size_t)c0*2;
    #pragma unroll
    for (int i = 0; i < 8; ++i) {
      int off = (w*8 + i)*1024 + l*16;
      int row = off >> 8, col = off & 255;
      size_t src = (size_t)row*(LC*2) + (col ^ ((row & 7) << 4));
      GLOAD_LDS(gb + src, (char*)buf + off);
    }
  }

  // single-tile softmax (no rescale needed: one c-tile per block)
  float tm[4] = {-1e30f,-1e30f,-1e30f,-1e30f};
  #pragma unroll
  for (int f = 0; f < 8; ++f) {
    #pragma unroll
    for (int r = 0; r < 4; ++r) { s[f][r] += s0v[f]; tm[r] = fmaxf(tm[r], s[f][r]); }
  }
  #pragma unroll
  for (int r = 0; r < 4; ++r) {
    #pragma unroll
    for (int m = 1; m < 16; m <<= 1) tm[r] = fmaxf(tm[r], __shfl_xor(tm[r], m));
  }
  float psum[4] = {0.f,0.f,0.f,0.f};
  #pragma unroll
  for (int f = 0; f < 8; ++f) {
    #pragma unroll
    for (int r = 0; r < 4; ++r) {
      float p = exp2f((s[f][r] - tm[r]) * L2E);
      psum[r] += p;
      Pl[w*16 + lg*4 + r][f*16 + lj] = f2bf(p);
    }
  }
  #pragma unroll
  for (int r = 0; r < 4; ++r) {
    #pragma unroll
    for (int m = 1; m < 16; m <<= 1) psum[r] += __shfl_xor(psum[r], m);
  }
  int pbase = (b*8 + qb)*SP + sp;
  if (lj == 0) {
    #pragma unroll
    for (int r = 0; r < 4; ++r) {
      mPart[pbase*64 + w*16 + lg*4 + r] = tm[r];
      lPart[pbase*64 + w*16 + lg*4 + r] = psum[r];
    }
  }
  __syncthreads();     // CbT staged (vmcnt drained) + Pl visible

  // PV: Tacc[q][d] += P[q][c] * C[c][d]
  f32x4 tacc[8];
  #pragma unroll
  for (int f = 0; f < 8; ++f) tacc[f] = (f32x4){0.f,0.f,0.f,0.f};
  #pragma unroll
  for (int ks = 0; ks < 4; ++ks) {
    bf16x8 ap = *reinterpret_cast<const bf16x8*>(&Pl[w*16 + lj][ks*32 + lg*8]);
    #pragma unroll
    for (int f = 0; f < 8; ++f)
      tacc[f] = MFMA(ap, ldb8(swz(buf, f*16 + lj, ks*64 + lg*16)), tacc[f]);
  }
  // coalesced bf16 partial store (permuted layout, matches combineT)
  #pragma unroll
  for (int f = 0; f < 8; ++f) {
    ushort4 hv;
    hv.x = f2bf(tacc[f][0]); hv.y = f2bf(tacc[f][1]);
    hv.z = f2bf(tacc[f][2]); hv.w = f2bf(tacc[f][3]);
    *reinterpret_cast<ushort4*>(TaccP + (((size_t)pbase*4 + w)*8 + f)*256 + lj*16 + lg*4) = hv;
  }
}

// ---------------- K1b: combine c-split partials -> TbT ----------------
// grid 256 = 16 b x 8 qb x 2 d-half
__global__ void combineT(const float* __restrict__ mPart, const float* __restrict__ lPart,
                         const u16* __restrict__ TaccP, u16* __restrict__ TbT){
  __shared__ float fac[SP][64];
  __shared__ u16 Tt[64][68];
  int blk = blockIdx.x;
  int b = blk >> 4, qb = (blk >> 1) & 7, dh = blk & 1;
  int t = threadIdx.x;
  int base = (b*8 + qb)*SP;
  if (t < 64) {
    float m_[SP], mm = -1e30f;
    #pragma unroll
    for (int p = 0; p < SP; ++p) { m_[p] = mPart[(base+p)*64 + t]; mm = fmaxf(mm, m_[p]); }
    float lt = 0.f, e[SP];
    #pragma unroll
    for (int p = 0; p < SP; ++p) {
      e[p] = exp2f((m_[p] - mm) * L2E);
      lt += lPart[(base+p)*64 + t] * e[p];
    }
    float il = 1.0f / lt;
    #pragma unroll
    for (int p = 0; p < SP; ++p) fac[p][t] = e[p] * il;
  }
  __syncthreads();
  int lj = t >> 4, lg = (t >> 2) & 3, r = t & 3;
  for (int w = 0; w < 4; ++w) {
    int q = w*16 + lg*4 + r;
    for (int fi = 0; fi < 4; ++fi) {
      int f = dh*4 + fi;
      float acc = 0.f;
      #pragma unroll
      for (int p = 0; p < SP; ++p)
        acc += bf2f(TaccP[(((size_t)(base+p)*4 + w)*8 + f)*256 + t]) * fac[p][q];
      Tt[q][fi*16 + lj] = f2bf(acc);
    }
  }
  __syncthreads();
  for (int k = 0; k < 4; ++k) {          // 64 d x 16 q-groups of 4 = 1024 chunks
    int ch = t + (k << 8); int dl = ch >> 4, q4 = (ch & 15) << 2;
    u32 lo = (u32)Tt[q4][dl]   | ((u32)Tt[q4+1][dl] << 16);
    u32 hi = (u32)Tt[q4+2][dl] | ((u32)Tt[q4+3][dl] << 16);
    uint2 u; u.x = lo; u.y = hi;
    *reinterpret_cast<uint2*>(TbT + ((size_t)(b*DD + dh*64 + dl))*LQ + qb*64 + q4) = u;
  }
}

// ---------------- K2: row-softmax + A + Bt + epilogue ----------------
__global__ void fused_out(const float* __restrict__ Cf, const u16* __restrict__ Cwb,
                          const u16* __restrict__ Qb, const u16* __restrict__ QbT,
                          const u16* __restrict__ TbT, const float* __restrict__ sub1,
                          float* __restrict__ out){
  __shared__ char smem[33792];
  __shared__ float red[4][32];
  u16*   Pl  = (u16*)smem;              // [32][520]
  float* avl = (float*)smem;            // [32][132]
  float* bvl = avl + 32*132;
  int bid = blockIdx.x;
  int id = (bid & 7) * 128 + (bid >> 3);
  int b = id >> 6, ctile = id & 63, c0 = ctile * 32;
  int w = threadIdx.x >> 6, l = threadIdx.x & 63;
  int lj = l & 15, lg = l >> 4;

  f32x4 s[2][8];
  #pragma unroll
  for (int rf = 0; rf < 2; ++rf)
    #pragma unroll
    for (int f = 0; f < 8; ++f) s[rf][f] = (f32x4){0.f,0.f,0.f,0.f};

  #pragma unroll
  for (int ks = 0; ks < 4; ++ks) {
    bf16x8 ah[2];
    #pragma unroll
    for (int rf = 0; rf < 2; ++rf)
      ah[rf] = ldb8(Cwb + ((size_t)(b*LC + c0 + rf*16 + lj))*DD + ks*32 + lg*8);
    #pragma unroll
    for (int f = 0; f < 8; ++f) {
      bf16x8 qv = ldb8(Qb + ((size_t)(b*LQ + w*128 + f*16 + lj))*DD + ks*32 + lg*8);
      #pragma unroll
      for (int rf = 0; rf < 2; ++rf) s[rf][f] = MFMA(ah[rf], qv, s[rf][f]);
    }
  }
  float tm[2][4];
  #pragma unroll
  for (int rf = 0; rf < 2; ++rf)
    #pragma unroll
    for (int r = 0; r < 4; ++r) tm[rf][r] = -1e30f;
  #pragma unroll
  for (int f = 0; f < 8; ++f) {
    float s1v = sub1[b*LQ + w*128 + f*16 + lj];
    #pragma unroll
    for (int rf = 0; rf < 2; ++rf)
      #pragma unroll
      for (int r = 0; r < 4; ++r) { s[rf][f][r] += s1v; tm[rf][r] = fmaxf(tm[rf][r], s[rf][f][r]); }
  }
  #pragma unroll
  for (int rf = 0; rf < 2; ++rf)
    #pragma unroll
    for (int r = 0; r < 4; ++r) {
      #pragma unroll
      for (int m = 1; m < 16; m <<= 1) tm[rf][r] = fmaxf(tm[rf][r], __shfl_xor(tm[rf][r], m));
    }
  if (lj == 0) {
    #pragma unroll
    for (int rf = 0; rf < 2; ++rf)
      #pragma unroll
      for (int r = 0; r < 4; ++r) red[w][rf*16 + lg*4 + r] = tm[rf][r];
  }
  __syncthreads();
  float mfin[2][4];
  #pragma unroll
  for (int rf = 0; rf < 2; ++rf)
    #pragma unroll
    for (int r = 0; r < 4; ++r) {
      int row = rf*16 + lg*4 + r;
      mfin[rf][r] = fmaxf(fmaxf(red[0][row], red[1][row]), fmaxf(red[2][row], red[3][row]));
    }
  __syncthreads();
  float ps[2][4] = {{0.f,0.f,0.f,0.f},{0.f,0.f,0.f,0.f}};
  #pragma unroll
  for (int f = 0; f < 8; ++f)
    #pragma unroll
    for (int rf = 0; rf < 2; ++rf)
      #pragma unroll
      for (int r = 0; r < 4; ++r) {
        float p = exp2f((s[rf][f][r] - mfin[rf][r]) * L2E);
        s[rf][f][r] = p;
        ps[rf][r] += p;
      }
  #pragma unroll
  for (int rf = 0; rf < 2; ++rf)
    #pragma unroll
    for (int r = 0; r < 4; ++r) {
      #pragma unroll
      for (int m = 1; m < 16; m <<= 1) ps[rf][r] += __shfl_xor(ps[rf][r], m);
    }
  if (lj == 0) {
    #pragma unroll
    for (int rf = 0; rf < 2; ++rf)
      #pragma unroll
      for (int r = 0; r < 4; ++r) red[w][rf*16 + lg*4 + r] = ps[rf][r];
  }
  __syncthreads();
  float linv[2][4];
  #pragma unroll
  for (int rf = 0; rf < 2; ++rf)
    #pragma unroll
    for (int r = 0; r < 4; ++r) {
      int row = rf*16 + lg*4 + r;
      linv[rf][r] = 1.0f / (red[0][row] + red[1][row] + red[2][row] + red[3][row]);
    }
  #pragma unroll
  for (int f = 0; f < 8; ++f)
    #pragma unroll
    for (int rf = 0; rf < 2; ++rf)
      #pragma unroll
      for (int r = 0; r < 4; ++r)
        Pl[(rf*16 + lg*4 + r)*520 + w*128 + f*16 + lj] = f2bf(s[rf][f][r]);
  __syncthreads();

  f32x4 aA[2][2], aB[2][2];
  #pragma unroll
  for (int rf = 0; rf < 2; ++rf)
    #pragma unroll
    for (int cf = 0; cf < 2; ++cf) { aA[rf][cf] = (f32x4){0.f,0.f,0.f,0.f}; aB[rf][cf] = (f32x4){0.f,0.f,0.f,0.f}; }
  for (int ks = 0; ks < 16; ++ks) {
    bf16x8 pa[2];
    #pragma unroll
    for (int rf = 0; rf < 2; ++rf)
      pa[rf] = ldb8(Pl + (rf*16 + lj)*520 + ks*32 + lg*8);
    #pragma unroll
    for (int cf = 0; cf < 2; ++cf) {
      size_t bo = ((size_t)(b*DD + w*32 + cf*16 + lj))*LQ + ks*32 + lg*8;
      bf16x8 qv = ldb8(QbT + bo);
      bf16x8 tv = ldb8(TbT + bo);
      #pragma unroll
      for (int rf = 0; rf < 2; ++rf) {
        aA[rf][cf] = MFMA(pa[rf], qv, aA[rf][cf]);
        aB[rf][cf] = MFMA(pa[rf], tv, aB[rf][cf]);
      }
    }
  }
  __syncthreads();
  #pragma unroll
  for (int rf = 0; rf < 2; ++rf)
    #pragma unroll
    for (int cf = 0; cf < 2; ++cf)
      #pragma unroll
      for (int r = 0; r < 4; ++r) {
        int row = rf*16 + lg*4 + r;
        int d   = w*32 + cf*16 + lj;
        avl[row*132 + d] = aA[rf][cf][r] * linv[rf][r];
        bvl[row*132 + d] = aB[rf][cf][r] * linv[rf][r];
      }
  __syncthreads();
  for (int i = 0; i < 16; ++i) {
    int row = i*2 + (l >> 5), d4 = l & 31;
    size_t grow = (size_t)(b*LC + c0 + row);
    float4 o;
    if (w == 0) {
      o = *reinterpret_cast<const float4*>(Cf + grow*DD + d4*4);
    } else if (w == 1) {
      o = *reinterpret_cast<const float4*>(avl + row*132 + d4*4);
    } else if (w == 2) {
      float4 c = *reinterpret_cast<const float4*>(Cf + grow*DD + d4*4);
      float4 a = *reinterpret_cast<const float4*>(avl + row*132 + d4*4);
      o.x = c.x*a.x; o.y = c.y*a.y; o.z = c.z*a.z; o.w = c.w*a.w;
    } else {
      float4 c = *reinterpret_cast<const float4*>(Cf + grow*DD + d4*4);
      float4 bb = *reinterpret_cast<const float4*>(bvl + row*132 + d4*4);
      o.x = c.x*bb.x; o.y = c.y*bb.y; o.z = c.z*bb.z; o.w = c.w*bb.w;
    }
    *reinterpret_cast<float4*>(out + grow*512 + w*128 + d4*4) = o;
  }
}

// ---------------- launch ----------------
extern "C" void kernel_launch(void* const* d_in, const int* in_sizes, int n_in,
                              void* d_out, int out_size, void* d_ws, size_t ws_size,
                              hipStream_t stream) {
  const float* C     = (const float*)d_in[0];
  const float* Q     = (const float*)d_in[1];
  const float* w4C   = (const float*)d_in[4];
  const float* w4Q   = (const float*)d_in[5];
  const float* w4mlu = (const float*)d_in[6];
  float* out = (float*)d_out;

  char* ws = (char*)d_ws;
  size_t off = 0;
  auto alloc = [&](size_t bytes) -> void* {
    void* p = ws + off;
    off += (bytes + 255) & ~(size_t)255;
    return p;
  };
  float* sub0  = (float*)alloc((size_t)B_*LC*4);
  float* sub1  = (float*)alloc((size_t)B_*LQ*4);
  u16*   Cwb   = (u16*)  alloc((size_t)B_*LC*DD*2);
  u16*   CbT   = (u16*)  alloc((size_t)B_*DD*LC*2);
  u16*   Qb    = (u16*)  alloc((size_t)B_*LQ*DD*2);
  u16*   QbT   = (u16*)  alloc((size_t)B_*DD*LQ*2);
  u16*   TbT   = (u16*)  alloc((size_t)B_*DD*LQ*2);
  float* mPart = (float*)alloc((size_t)B_*8*SP*64*4);
  float* lPart = (float*)alloc((size_t)B_*8*SP*64*4);
  u16*   TaccP = (u16*)  alloc((size_t)B_*8*SP*64*DD*2);

  hipLaunchKernelGGL(prep, dim3(640), dim3(256), 0, stream,
                     C, Q, w4C, w4Q, w4mlu, Cwb, CbT, Qb, QbT, sub0, sub1);
  hipLaunchKernelGGL(flashT, dim3(2048), dim3(256), 0, stream,
                     Qb, Cwb, CbT, sub0, mPart, lPart, TaccP);
  hipLaunchKernelGGL(combineT, dim3(256), dim3(256), 0, stream,
                     mPart, lPart, TaccP, TbT);
  hipLaunchKernelGGL(fused_out, dim3(1024), dim3(256), 0, stream,
                     C, Cwb, Qb, QbT, TbT, sub1, out);
}